// Round 10
// baseline (878.936 us; speedup 1.0000x reference)
//
#include <hip/hip_runtime.h>
#include <hip/hip_bf16.h>
#include <math.h>

typedef __hip_bfloat16 bf16;

#define AFEA 128          // atom_fea_len
#define NBRF 41           // nbr_fea_len
#define IN2 297           // 2A + NBR
#define KP 320            // MFMA-padded K (10 chunks of 32)
#define TSTR 328          // LDS A-tile row stride in shorts (656 B, 16B-aligned)
#define ROWS 32           // A-tile rows per block (LDS 21 KB -> 6 blocks/CU)
#define P1 64             // bn1 stat partial copies
#define P2 16             // bn2 stat partial copies

typedef __attribute__((ext_vector_type(8))) short bf16x8;   // MFMA A/B frag
typedef __attribute__((ext_vector_type(4))) float f32x4;    // MFMA C/D frag

__device__ __forceinline__ unsigned short bfbits(float x) {
    bf16 h = __float2bfloat16(x);
    return *(unsigned short*)&h;
}
__device__ __forceinline__ unsigned int pack2(float x, float y) {
    return (unsigned int)bfbits(x) | ((unsigned int)bfbits(y) << 16);
}
__device__ __forceinline__ float blo(unsigned int u) { return __uint_as_float(u << 16); }
__device__ __forceinline__ float bhi(unsigned int u) { return __uint_as_float(u & 0xffff0000u); }
__device__ __forceinline__ float leakyf(float x) { return x >= 0.f ? x : 0.01f * x; }
__device__ __forceinline__ float sigmoid_fast(float x) { return 1.f / (1.f + __expf(-x)); }
__device__ __forceinline__ float softplus_fast(float x) {
    return fmaxf(x, 0.f) + __logf(1.f + __expf(-fabsf(x)));
}

// ---------------- nbr_fea (f32 [NM][41]) -> nbr16 (bf16 [NM][64], zero-padded) ----------------
__global__ void nbr16_kernel(const float* __restrict__ nbr, unsigned short* __restrict__ nbr16,
                             int NM)
{
    int i = blockIdx.x * blockDim.x + threadIdx.x;
    if (i >= NM * 64) return;
    int k = i & 63, e = i >> 6;
    nbr16[i] = (k < NBRF) ? bfbits(nbr[(size_t)e * NBRF + k]) : 0;
}

// ---------------- embedding: af = atom_fea @ emb_W.T + emb_b (W staged in LDS) ----------------
__global__ __launch_bounds__(256) void embed_kernel(
    const float* __restrict__ xf, const float* __restrict__ W,
    const float* __restrict__ b, float* __restrict__ af,
    unsigned short* __restrict__ af16, int N)
{
    __shared__ float W_s[92 * 128];
    __shared__ float xs[16 * 92];
    int t = threadIdx.x;
    int n0 = blockIdx.x * 16;
    for (int i = t; i < 92 * 128; i += 256) {
        int o = i / 92, k = i - o * 92;
        W_s[k * 128 + o] = W[i];
    }
    for (int i = t; i < 16 * 92; i += 256) {
        int a = i / 92, k = i - a * 92;
        int n = n0 + a;
        xs[i] = (n < N) ? xf[(size_t)n * 92 + k] : 0.f;
    }
    __syncthreads();
    int o = t & 127, h = t >> 7;
    float bias = b[o];
    for (int a = h; a < 16; a += 2) {
        int n = n0 + a;
        if (n >= N) break;
        float acc = bias;
        const float* xr = xs + a * 92;
        #pragma unroll 4
        for (int k = 0; k < 92; k++) acc += xr[k] * W_s[k * 128 + o];
        af[(size_t)n * AFEA + o] = acc;
        af16[(size_t)n * AFEA + o] = bfbits(acc);
    }
}

// ---------------- prep: zero stat partials + build Wb (bf16, [KP/32][256][32]) ----------------
__global__ void prep_kernel(const float* __restrict__ Wa, size_t offA,
                            const float* __restrict__ Wsrc, size_t offB,
                            unsigned short* __restrict__ Wb,
                            float* __restrict__ zbuf, int nz)
{
    int i = blockIdx.x * blockDim.x + threadIdx.x;   // grid covers KP*256 = 81920
    if (i < nz) zbuf[i] = 0.f;
    if (i >= KP * 256) return;
    int t32 = i & 31;
    int c = (i >> 5) & 255;
    int kc = i >> 13;
    int k = kc * 32 + t32;
    float v = 0.f;
    if (k < IN2) v = (c < 128) ? Wa[offA + (size_t)c * IN2 + k]
                               : Wsrc[offB + (size_t)(c - 128) * IN2 + k];
    Wb[i] = bfbits(v);
}

// ---------------- MFMA GEMM: g_t[col][bond] = (total @ W.T + bias)^T (+ BN stats) ----------------
// 32-row tiles, 6 blocks/CU target. Wave w: 32 rows x cols [w*64, w*64+64).
__global__ __launch_bounds__(256, 6) void gemm_mfma_kernel(
    const unsigned short* __restrict__ af16, const unsigned short* __restrict__ nbr16,
    const int* __restrict__ idx, const unsigned short* __restrict__ Wb,
    const float* __restrict__ bias_a, size_t boffA,
    const float* __restrict__ bias_b, size_t boffB,
    unsigned short* __restrict__ g_t, float* __restrict__ part1,
    int NM, int M)
{
    __shared__ unsigned short a_tile[ROWS * TSTR];   // 20992 B
    const int t = threadIdx.x;
    const int e0 = blockIdx.x * ROWS;

    // ---- stage A-tile: 32 rows, 8 threads/row, all 16B vector ops ----
    {
        int row = t >> 3, p = t & 7;
        int e = e0 + row;
        int n = e / M;
        int j = idx[e];
        const uint4* srcn = (const uint4*)(af16 + (size_t)n * AFEA);
        const uint4* srcj = (const uint4*)(af16 + (size_t)j * AFEA);
        const uint4* srcb = (const uint4*)(nbr16 + (size_t)e * 64);
        uint4* dst = (uint4*)(a_tile + row * TSTR);
        #pragma unroll
        for (int u = 0; u < 2; u++) dst[p + 8 * u] = srcn[p + 8 * u];
        #pragma unroll
        for (int u = 0; u < 2; u++) dst[16 + p + 8 * u] = srcj[p + 8 * u];
        dst[32 + p] = srcb[p];
    }
    __syncthreads();

    const int l = t & 63, w = t >> 6;
    const int m16 = l & 15, q = l >> 4;
    const int colbase = w * 64;

    f32x4 acc[2][4];
    #pragma unroll
    for (int rt = 0; rt < 2; rt++)
        #pragma unroll
        for (int ct = 0; ct < 4; ct++) acc[rt][ct] = (f32x4)0.f;

    const unsigned short* abase = a_tile + m16 * TSTR + q * 8;
    const unsigned short* bbase = Wb + (size_t)(colbase + m16) * 32 + q * 8;

    bf16x8 bcur[4];
    #pragma unroll
    for (int ct = 0; ct < 4; ct++)
        bcur[ct] = *(const bf16x8*)(bbase + ct * 512);

    #pragma unroll
    for (int kc = 0; kc < KP / 32; kc++) {
        bf16x8 a[2], bnext[4];
        if (kc < KP / 32 - 1) {
            #pragma unroll
            for (int ct = 0; ct < 4; ct++)
                bnext[ct] = *(const bf16x8*)(bbase + (kc + 1) * 8192 + ct * 512);
        }
        #pragma unroll
        for (int rt = 0; rt < 2; rt++)
            a[rt] = *(const bf16x8*)(abase + rt * 16 * TSTR + kc * 32);
        #pragma unroll
        for (int rt = 0; rt < 2; rt++)
            #pragma unroll
            for (int ct = 0; ct < 4; ct++)
                acc[rt][ct] = __builtin_amdgcn_mfma_f32_16x16x32_bf16(
                    a[rt], bcur[ct], acc[rt][ct], 0, 0, 0);
        if (kc < KP / 32 - 1) {
            #pragma unroll
            for (int ct = 0; ct < 4; ct++) bcur[ct] = bnext[ct];
        }
    }

    // ---- epilogue: bias; packed uint2 stores to transposed g_t; stats ----
    float* pp = part1 + (size_t)(blockIdx.x & (P1 - 1)) * 512;
    #pragma unroll
    for (int ct = 0; ct < 4; ct++) {
        int col = colbase + ct * 16 + m16;
        float bias = (col < 128) ? bias_a[boffA + col] : bias_b[boffB + col - 128];
        float ps = 0.f, pq = 0.f;
        #pragma unroll
        for (int rt = 0; rt < 2; rt++) {
            float v0 = acc[rt][ct][0] + bias;
            float v1 = acc[rt][ct][1] + bias;
            float v2 = acc[rt][ct][2] + bias;
            float v3 = acc[rt][ct][3] + bias;
            ps += (v0 + v1) + (v2 + v3);
            pq += (v0 * v0 + v1 * v1) + (v2 * v2 + v3 * v3);
            uint2 pk;
            pk.x = pack2(v0, v1);
            pk.y = pack2(v2, v3);
            *(uint2*)(g_t + (size_t)col * NM + e0 + rt * 16 + q * 4) = pk;
        }
        ps += __shfl_xor(ps, 16); ps += __shfl_xor(ps, 32);
        pq += __shfl_xor(pq, 16); pq += __shfl_xor(pq, 32);
        if (q == 0) {
            atomicAdd(&pp[col], ps);
            atomicAdd(&pp[256 + col], pq);
        }
    }
}

// ---------------- fold BN stats (P partial copies) into affine a,c ----------------
__global__ void finalize_kernel(
    const float* __restrict__ part, int P, int nch,
    const float* __restrict__ ga, size_t goA, const float* __restrict__ gb, size_t goB,
    const float* __restrict__ ba, size_t boA, const float* __restrict__ bb, size_t boB,
    float* __restrict__ a_out, float* __restrict__ c_out, float count)
{
    int c = threadIdx.x;
    if (c >= nch) return;
    int stride = 2 * nch;
    float s = 0.f, q = 0.f;
    for (int p = 0; p < P; p++) {
        s += part[(size_t)p * stride + c];
        q += part[(size_t)p * stride + nch + c];
    }
    float mean = s / count;
    float var = fmaxf(q / count - mean * mean, 0.f);
    float g  = (c < 128) ? ga[goA + c] : gb[goB + c - 128];
    float be = (c < 128) ? ba[boA + c] : bb[boB + c - 128];
    float a = g * rsqrtf(var + 1e-5f);
    a_out[c] = a;
    c_out[c] = be - mean * a;
}

// ---------------- conv gate (transposed g): sum over M, write summed, + bn2 stats ----------------
// grid: ceil(N/64)*4 blocks of 256 (4 waves). Wave w of block b: ch-pairs
// [(b&3)*16 + w*4, +4) for 64 atoms (lanes). bn2 stats fused via wave shfl.
__global__ __launch_bounds__(256) void gate_kernel(
    const unsigned short* __restrict__ gt, const float* __restrict__ a1,
    const float* __restrict__ c1, float* __restrict__ summed,
    float* __restrict__ part2, int N, int M, int NM)
{
    int t = threadIdx.x, w = t >> 6, l = t & 63;
    int n = (blockIdx.x >> 2) * 64 + l;
    bool act = (n < N);
    int cp0 = (blockIdx.x & 3) * 16 + w * 4;
    size_t col0 = (size_t)n * M;
    float* pp = part2 + (size_t)(blockIdx.x & (P2 - 1)) * 256;
    #pragma unroll
    for (int cpi = 0; cpi < 4; cpi++) {
        int chf = 2 * (cp0 + cpi);          // filter channels chf, chf+1
        int chc = 128 + chf;                // core channels
        float s0 = 0.f, s1 = 0.f;
        if (act) {
            const uint2* rf0 = (const uint2*)(gt + (size_t)chf * NM + col0);
            const uint2* rf1 = (const uint2*)(gt + (size_t)(chf + 1) * NM + col0);
            const uint2* rc0 = (const uint2*)(gt + (size_t)chc * NM + col0);
            const uint2* rc1 = (const uint2*)(gt + (size_t)(chc + 1) * NM + col0);
            float aF0 = a1[chf], cF0 = c1[chf], aF1 = a1[chf + 1], cF1 = c1[chf + 1];
            float aC0 = a1[chc], cC0 = c1[chc], aC1 = a1[chc + 1], cC1 = c1[chc + 1];
            #pragma unroll
            for (int u = 0; u < 3; u++) {   // 3 x uint2 = 12 bonds
                uint2 f0 = rf0[u], f1 = rf1[u], k0 = rc0[u], k1 = rc1[u];
                #pragma unroll
                for (int h = 0; h < 4; h++) {
                    unsigned int fw0 = (h < 2) ? f0.x : f0.y;
                    unsigned int fw1 = (h < 2) ? f1.x : f1.y;
                    unsigned int kw0 = (h < 2) ? k0.x : k0.y;
                    unsigned int kw1 = (h < 2) ? k1.x : k1.y;
                    float gf0 = (h & 1) ? bhi(fw0) : blo(fw0);
                    float gf1 = (h & 1) ? bhi(fw1) : blo(fw1);
                    float gc0 = (h & 1) ? bhi(kw0) : blo(kw0);
                    float gc1 = (h & 1) ? bhi(kw1) : blo(kw1);
                    s0 += sigmoid_fast(fmaf(aF0, gf0, cF0)) * leakyf(fmaf(aC0, gc0, cC0));
                    s1 += sigmoid_fast(fmaf(aF1, gf1, cF1)) * leakyf(fmaf(aC1, gc1, cC1));
                }
            }
            *(float2*)(summed + (size_t)n * AFEA + chf) = make_float2(s0, s1);
        }
        // bn2 stats: reduce over 64 atoms (lanes)
        float q0 = s0 * s0, q1 = s1 * s1;
        #pragma unroll
        for (int sft = 32; sft > 0; sft >>= 1) {
            s0 += __shfl_xor(s0, sft);
            s1 += __shfl_xor(s1, sft);
            q0 += __shfl_xor(q0, sft);
            q1 += __shfl_xor(q1, sft);
        }
        if (l == 0) {
            atomicAdd(&pp[chf], s0);
            atomicAdd(&pp[chf + 1], s1);
            atomicAdd(&pp[128 + chf], q0);
            atomicAdd(&pp[128 + chf + 1], q1);
        }
    }
}

// ---------------- residual update: af = leaky(af + bn2(summed)); also af16 ----------------
__global__ void afup_kernel(float* __restrict__ af, unsigned short* __restrict__ af16,
                            const float* __restrict__ summed,
                            const float* __restrict__ a2, const float* __restrict__ c2, int total)
{
    int i = blockIdx.x * blockDim.x + threadIdx.x;
    if (i >= total) return;
    int o = i & 127;
    float v = af[i] + a2[o] * summed[i] + c2[o];
    v = (v >= 0.f) ? v : 0.01f * v;
    af[i] = v;
    af16[i] = bfbits(v);
}

// ---------------- head (transposed g): thread owns 2 bonds; float4 out ----------------
__global__ __launch_bounds__(256) void head_kernel(
    const unsigned short* __restrict__ gt, const float* __restrict__ a1,
    const float* __restrict__ c1,
    const float* __restrict__ w2d, const float* __restrict__ b2d,
    const float* __restrict__ w2c, const float* __restrict__ b2c,
    const float* __restrict__ pos, const float* __restrict__ off,
    const float* __restrict__ cells, const int* __restrict__ idx,
    float* __restrict__ out, int NM, int M)
{
    int e = blockIdx.x * 512 + threadIdx.x * 2;
    if (e >= NM) return;
    float sd0 = 0.f, sd1 = 0.f, sc0 = 0.f, sc1 = 0.f;
    #pragma unroll 4
    for (int ch = 0; ch < 128; ch++) {
        unsigned int u = *(const unsigned int*)(gt + (size_t)ch * NM + e);
        float a = a1[ch], c = c1[ch], wv = w2d[ch];
        sd0 += leakyf(fmaf(a, blo(u), c)) * wv;
        sd1 += leakyf(fmaf(a, bhi(u), c)) * wv;
    }
    #pragma unroll 4
    for (int ch = 128; ch < 256; ch++) {
        unsigned int u = *(const unsigned int*)(gt + (size_t)ch * NM + e);
        float a = a1[ch], c = c1[ch], wv = w2c[ch - 128];
        sc0 += softplus_fast(fmaf(a, blo(u), c)) * wv;
        sc1 += softplus_fast(fmaf(a, bhi(u), c)) * wv;
    }
    float dist[2];
    #pragma unroll
    for (int h = 0; h < 2; h++) {
        int eb = e + h;
        int n = eb / M;
        int j = idx[eb];
        float o0 = off[(size_t)eb * 3 + 0];
        float o1 = off[(size_t)eb * 3 + 1];
        float o2 = off[(size_t)eb * 3 + 2];
        float d0 = o0 * cells[0] + o1 * cells[3] + o2 * cells[6] + pos[(size_t)j * 3 + 0] - pos[(size_t)n * 3 + 0];
        float d1 = o0 * cells[1] + o1 * cells[4] + o2 * cells[7] + pos[(size_t)j * 3 + 1] - pos[(size_t)n * 3 + 1];
        float d2 = o0 * cells[2] + o1 * cells[5] + o2 * cells[8] + pos[(size_t)j * 3 + 2] - pos[(size_t)n * 3 + 2];
        dist[h] = sqrtf(d0 * d0 + d1 * d1 + d2 * d2 + 1e-12f);
    }
    float bd = b2d[0], bc = b2c[0];
    float4 o4;
    o4.x = leakyf(sd0 + bd + dist[0]);
    o4.y = softplus_fast(sc0 + bc);
    o4.z = leakyf(sd1 + bd + dist[1]);
    o4.w = softplus_fast(sc1 + bc);
    *(float4*)(out + (size_t)e * 2) = o4;
}

extern "C" void kernel_launch(void* const* d_in, const int* in_sizes, int n_in,
                              void* d_out, int out_size, void* d_ws, size_t ws_size,
                              hipStream_t stream) {
    const float* atom_fea   = (const float*)d_in[0];
    const float* nbr_fea    = (const float*)d_in[1];
    const float* nbr_off    = (const float*)d_in[2];
    const float* atom_pos   = (const float*)d_in[3];
    const float* cells      = (const float*)d_in[4];
    const int*   idx        = (const int*)d_in[5];
    const float* emb_W      = (const float*)d_in[6];
    const float* emb_b      = (const float*)d_in[7];
    const float* convs_W    = (const float*)d_in[8];
    const float* convs_b    = (const float*)d_in[9];
    const float* bn1g       = (const float*)d_in[10];
    const float* bn1b       = (const float*)d_in[11];
    const float* bn2g       = (const float*)d_in[12];
    const float* bn2b       = (const float*)d_in[13];
    const float* dist_W     = (const float*)d_in[14];
    const float* dist_b     = (const float*)d_in[15];
    const float* dist_bn_g  = (const float*)d_in[16];
    const float* dist_bn_b  = (const float*)d_in[17];
    const float* dist2_W    = (const float*)d_in[18];
    const float* dist2_b    = (const float*)d_in[19];
    const float* const_W    = (const float*)d_in[20];
    const float* const_b    = (const float*)d_in[21];
    const float* const_bn_g = (const float*)d_in[22];
    const float* const_bn_b = (const float*)d_in[23];
    const float* const2_W   = (const float*)d_in[24];
    const float* const2_b   = (const float*)d_in[25];

    const int N  = in_sizes[0] / 92;
    const int M  = in_sizes[5] / N;
    const int NM = N * M;

    char* ws = (char*)d_ws;
    size_t off = 0;
    float* af             = (float*)(ws + off); off += (size_t)N * AFEA * 4;
    float* summed         = (float*)(ws + off); off += (size_t)N * AFEA * 4;
    unsigned short* af16  = (unsigned short*)(ws + off); off += (size_t)N * AFEA * 2;
    unsigned short* Wb    = (unsigned short*)(ws + off); off += (size_t)256 * KP * 2;
    float* part1          = (float*)(ws + off); off += (size_t)P1 * 512 * 4;
    float* part2          = (float*)(ws + off); off += (size_t)P2 * 256 * 4;
    float* aff1           = (float*)(ws + off); off += 512 * 4;
    float* aff2           = (float*)(ws + off); off += 256 * 4;
    unsigned short* g_t   = (unsigned short*)(ws + off); off += (size_t)NM * 256 * 2;
    unsigned short* nbr16 = (unsigned short*)(ws + off); off += (size_t)NM * 64 * 2;

    const int NPART = P1 * 512 + P2 * 256;   // part1+part2 contiguous

    nbr16_kernel<<<(NM * 64 + 255) / 256, 256, 0, stream>>>(nbr_fea, nbr16, NM);
    embed_kernel<<<(N + 15) / 16, 256, 0, stream>>>(atom_fea, emb_W, emb_b, af, af16, N);

    const int gblocks = NM / ROWS;
    const int gateblocks = ((N + 63) / 64) * 4;
    const int prepblocks = (256 * KP + 255) / 256;

    for (int i = 0; i < 3; i++) {
        size_t wo  = (size_t)i * 256 * IN2;
        size_t bo  = (size_t)i * 256;
        size_t b2o = (size_t)i * 128;

        prep_kernel<<<prepblocks, 256, 0, stream>>>(
            convs_W, wo, convs_W, wo + (size_t)128 * IN2, Wb, part1, NPART);
        gemm_mfma_kernel<<<gblocks, 256, 0, stream>>>(
            af16, nbr16, idx, Wb, convs_b, bo, convs_b, bo + 128,
            g_t, part1, NM, M);
        finalize_kernel<<<1, 256, 0, stream>>>(
            part1, P1, 256, bn1g, bo, bn1g, bo + 128, bn1b, bo, bn1b, bo + 128,
            aff1, aff1 + 256, (float)NM);
        gate_kernel<<<gateblocks, 256, 0, stream>>>(
            g_t, aff1, aff1 + 256, summed, part2, N, M, NM);
        finalize_kernel<<<1, 256, 0, stream>>>(
            part2, P2, 128, bn2g, b2o, bn2g, b2o, bn2b, b2o, bn2b, b2o,
            aff2, aff2 + 128, (float)N);
        afup_kernel<<<(N * AFEA + 255) / 256, 256, 0, stream>>>(
            af, af16, summed, aff2, aff2 + 128, N * AFEA);
    }

    // heads: fused 297->256 GEMM (cols 0..127 dist, 128..255 const)
    {
        prep_kernel<<<prepblocks, 256, 0, stream>>>(
            dist_W, 0, const_W, 0, Wb, part1, P1 * 512);
        gemm_mfma_kernel<<<gblocks, 256, 0, stream>>>(
            af16, nbr16, idx, Wb, dist_b, 0, const_b, 0,
            g_t, part1, NM, M);
        finalize_kernel<<<1, 256, 0, stream>>>(
            part1, P1, 256, dist_bn_g, 0, const_bn_g, 0, dist_bn_b, 0, const_bn_b, 0,
            aff1, aff1 + 256, (float)NM);
        head_kernel<<<(NM + 511) / 512, 256, 0, stream>>>(
            g_t, aff1, aff1 + 256, dist2_W, dist2_b, const2_W, const2_b,
            atom_pos, nbr_off, cells, idx, (float*)d_out, NM, M);
    }
}

// Round 11
// 683.411 us; speedup vs baseline: 1.2861x; 1.2861x over previous
//
#include <hip/hip_runtime.h>
#include <hip/hip_bf16.h>
#include <math.h>

typedef __hip_bfloat16 bf16;

#define AFEA 128          // atom_fea_len
#define NBRF 41           // nbr_fea_len
#define IN2 297           // 2A + NBR
#define KP 320            // MFMA-padded K (10 chunks of 32)
#define TSTR 328          // LDS A-tile row stride in shorts
#define ROWS 64           // A-tile rows: 64 = one full 128B line per channel in g_t (do NOT shrink)
#define P1 64             // bn1 stat partial copies
#define P2 16             // bn2 stat partial copies

typedef __attribute__((ext_vector_type(8))) short bf16x8;   // MFMA A/B frag
typedef __attribute__((ext_vector_type(4))) float f32x4;    // MFMA C/D frag

__device__ __forceinline__ unsigned short bfbits(float x) {
    bf16 h = __float2bfloat16(x);
    return *(unsigned short*)&h;
}
__device__ __forceinline__ unsigned int pack2(float x, float y) {
    return (unsigned int)bfbits(x) | ((unsigned int)bfbits(y) << 16);
}
__device__ __forceinline__ float blo(unsigned int u) { return __uint_as_float(u << 16); }
__device__ __forceinline__ float bhi(unsigned int u) { return __uint_as_float(u & 0xffff0000u); }
__device__ __forceinline__ float leakyf(float x) { return x >= 0.f ? x : 0.01f * x; }
__device__ __forceinline__ float sigmoid_fast(float x) { return 1.f / (1.f + __expf(-x)); }
__device__ __forceinline__ float softplus_fast(float x) {
    return fmaxf(x, 0.f) + __logf(1.f + __expf(-fabsf(x)));
}

// ---------------- nbr_fea (f32 [NM][41]) -> nbr16 (bf16 [NM][64], zero-padded) ----------------
__global__ void nbr16_kernel(const float* __restrict__ nbr, unsigned short* __restrict__ nbr16,
                             int NM)
{
    int i = blockIdx.x * blockDim.x + threadIdx.x;
    if (i >= NM * 64) return;
    int k = i & 63, e = i >> 6;
    nbr16[i] = (k < NBRF) ? bfbits(nbr[(size_t)e * NBRF + k]) : 0;
}

// ---------------- embedding: af = atom_fea @ emb_W.T + emb_b (W staged in LDS) ----------------
__global__ __launch_bounds__(256) void embed_kernel(
    const float* __restrict__ xf, const float* __restrict__ W,
    const float* __restrict__ b, float* __restrict__ af,
    unsigned short* __restrict__ af16, int N)
{
    __shared__ float W_s[92 * 128];
    __shared__ float xs[16 * 92];
    int t = threadIdx.x;
    int n0 = blockIdx.x * 16;
    for (int i = t; i < 92 * 128; i += 256) {
        int o = i / 92, k = i - o * 92;
        W_s[k * 128 + o] = W[i];
    }
    for (int i = t; i < 16 * 92; i += 256) {
        int a = i / 92, k = i - a * 92;
        int n = n0 + a;
        xs[i] = (n < N) ? xf[(size_t)n * 92 + k] : 0.f;
    }
    __syncthreads();
    int o = t & 127, h = t >> 7;
    float bias = b[o];
    for (int a = h; a < 16; a += 2) {
        int n = n0 + a;
        if (n >= N) break;
        float acc = bias;
        const float* xr = xs + a * 92;
        #pragma unroll 4
        for (int k = 0; k < 92; k++) acc += xr[k] * W_s[k * 128 + o];
        af[(size_t)n * AFEA + o] = acc;
        af16[(size_t)n * AFEA + o] = bfbits(acc);
    }
}

// ---------------- prep: zero stat partials + build Wb (bf16, [KP/32][256][32]) ----------------
__global__ void prep_kernel(const float* __restrict__ Wa, size_t offA,
                            const float* __restrict__ Wsrc, size_t offB,
                            unsigned short* __restrict__ Wb,
                            float* __restrict__ zbuf, int nz)
{
    int i = blockIdx.x * blockDim.x + threadIdx.x;   // grid covers KP*256 = 81920
    if (i < nz) zbuf[i] = 0.f;
    if (i >= KP * 256) return;
    int t32 = i & 31;
    int c = (i >> 5) & 255;
    int kc = i >> 13;
    int k = kc * 32 + t32;
    float v = 0.f;
    if (k < IN2) v = (c < 128) ? Wa[offA + (size_t)c * IN2 + k]
                               : Wsrc[offB + (size_t)(c - 128) * IN2 + k];
    Wb[i] = bfbits(v);
}

// ---------------- MFMA GEMM: g_t[col][bond] = (total @ W.T + bias)^T (+ BN stats) ----------------
// 64-row tiles (full-line g_t writes). B prefetch depth 2, issued before barrier.
__global__ __launch_bounds__(256, 3) void gemm_mfma_kernel(
    const unsigned short* __restrict__ af16, const unsigned short* __restrict__ nbr16,
    const int* __restrict__ idx, const unsigned short* __restrict__ Wb,
    const float* __restrict__ bias_a, size_t boffA,
    const float* __restrict__ bias_b, size_t boffB,
    unsigned short* __restrict__ g_t, float* __restrict__ part1,
    int NM, int M)
{
    __shared__ unsigned short a_tile[ROWS * TSTR];   // 41984 B
    const int t = threadIdx.x;
    const int e0 = blockIdx.x * ROWS;

    const int l = t & 63, w = t >> 6;
    const int m16 = l & 15, q = l >> 4;
    const int colbase = w * 64;
    const unsigned short* bbase = Wb + (size_t)(colbase + m16) * 32 + q * 8;

    // ---- stage A-tile: 64 rows, 4 threads/row, all 16B vector ops ----
    {
        int row = t >> 2, p = t & 3;
        int e = e0 + row;
        int n = e / M;
        int j = idx[e];
        const uint4* srcn = (const uint4*)(af16 + (size_t)n * AFEA);
        const uint4* srcj = (const uint4*)(af16 + (size_t)j * AFEA);
        const uint4* srcb = (const uint4*)(nbr16 + (size_t)e * 64);
        uint4* dst = (uint4*)(a_tile + row * TSTR);
        #pragma unroll
        for (int u = 0; u < 4; u++) dst[p + 4 * u] = srcn[p + 4 * u];
        #pragma unroll
        for (int u = 0; u < 4; u++) dst[16 + p + 4 * u] = srcj[p + 4 * u];
        #pragma unroll
        for (int u = 0; u < 2; u++) dst[32 + p + 4 * u] = srcb[p + 4 * u];
    }

    // ---- B prefetch (kc=0,1) issued before barrier: latency overlaps staging ----
    bf16x8 bcur[4], bnxt[4];
    #pragma unroll
    for (int ct = 0; ct < 4; ct++)
        bcur[ct] = *(const bf16x8*)(bbase + ct * 512);
    #pragma unroll
    for (int ct = 0; ct < 4; ct++)
        bnxt[ct] = *(const bf16x8*)(bbase + 8192 + ct * 512);

    __syncthreads();

    f32x4 acc[4][4];
    #pragma unroll
    for (int rt = 0; rt < 4; rt++)
        #pragma unroll
        for (int ct = 0; ct < 4; ct++) acc[rt][ct] = (f32x4)0.f;

    const unsigned short* abase = a_tile + m16 * TSTR + q * 8;

    #pragma unroll
    for (int kc = 0; kc < KP / 32; kc++) {
        bf16x8 a[4], b2[4];
        if (kc < KP / 32 - 2) {
            #pragma unroll
            for (int ct = 0; ct < 4; ct++)
                b2[ct] = *(const bf16x8*)(bbase + (kc + 2) * 8192 + ct * 512);
        }
        #pragma unroll
        for (int rt = 0; rt < 4; rt++)
            a[rt] = *(const bf16x8*)(abase + rt * 16 * TSTR + kc * 32);
        #pragma unroll
        for (int rt = 0; rt < 4; rt++)
            #pragma unroll
            for (int ct = 0; ct < 4; ct++)
                acc[rt][ct] = __builtin_amdgcn_mfma_f32_16x16x32_bf16(
                    a[rt], bcur[ct], acc[rt][ct], 0, 0, 0);
        if (kc < KP / 32 - 1) {
            #pragma unroll
            for (int ct = 0; ct < 4; ct++) bcur[ct] = bnxt[ct];
        }
        if (kc < KP / 32 - 2) {
            #pragma unroll
            for (int ct = 0; ct < 4; ct++) bnxt[ct] = b2[ct];
        }
    }

    // ---- epilogue: bias; packed uint2 stores to transposed g_t; stats ----
    float* pp = part1 + (size_t)(blockIdx.x & (P1 - 1)) * 512;
    #pragma unroll
    for (int ct = 0; ct < 4; ct++) {
        int col = colbase + ct * 16 + m16;
        float bias = (col < 128) ? bias_a[boffA + col] : bias_b[boffB + col - 128];
        float ps = 0.f, pq = 0.f;
        #pragma unroll
        for (int rt = 0; rt < 4; rt++) {
            float v0 = acc[rt][ct][0] + bias;
            float v1 = acc[rt][ct][1] + bias;
            float v2 = acc[rt][ct][2] + bias;
            float v3 = acc[rt][ct][3] + bias;
            ps += (v0 + v1) + (v2 + v3);
            pq += (v0 * v0 + v1 * v1) + (v2 * v2 + v3 * v3);
            uint2 pk;
            pk.x = pack2(v0, v1);
            pk.y = pack2(v2, v3);
            *(uint2*)(g_t + (size_t)col * NM + e0 + rt * 16 + q * 4) = pk;
        }
        ps += __shfl_xor(ps, 16); ps += __shfl_xor(ps, 32);
        pq += __shfl_xor(pq, 16); pq += __shfl_xor(pq, 32);
        if (q == 0) {
            atomicAdd(&pp[col], ps);
            atomicAdd(&pp[256 + col], pq);
        }
    }
}

// ---------------- conv gate: fused bn1-finalize + gate + bn2 stats ----------------
// grid: ceil(N/64)*4 blocks of 256 (4 waves). Wave w of block b: ch-pairs
// [(b&3)*16 + w*4, +4) -> 8 filter ch (fch0..+7) and 8 core ch (128+fch0..+7).
__global__ __launch_bounds__(256) void gate_kernel(
    const unsigned short* __restrict__ gt, const float* __restrict__ part1,
    const float* __restrict__ gamma, const float* __restrict__ beta,
    float* __restrict__ summed, float* __restrict__ part2,
    float cnt1, int N, int M, int NM)
{
    __shared__ float affA[4 * 16], affC[4 * 16];   // per-wave 16 channels
    int t = threadIdx.x, w = t >> 6, l = t & 63;
    int cp0 = (blockIdx.x & 3) * 16 + w * 4;
    int fch0 = 2 * cp0;

    // ---- fused finalize: lanes 0..15 reduce their channel's P1 partials ----
    if (l < 16) {
        int ch = (l < 8) ? (fch0 + l) : (128 + fch0 + (l - 8));
        float s = 0.f, qq = 0.f;
        #pragma unroll 8
        for (int p = 0; p < P1; p++) {
            s += part1[(size_t)p * 512 + ch];
            qq += part1[(size_t)p * 512 + 256 + ch];
        }
        float mean = s / cnt1;
        float var = fmaxf(qq / cnt1 - mean * mean, 0.f);
        float a = gamma[ch] * rsqrtf(var + 1e-5f);
        affA[w * 16 + l] = a;
        affC[w * 16 + l] = beta[ch] - mean * a;
    }
    __syncthreads();

    int n = (blockIdx.x >> 2) * 64 + l;
    bool act = (n < N);
    size_t col0 = (size_t)n * M;
    float* pp = part2 + (size_t)(blockIdx.x & (P2 - 1)) * 256;
    #pragma unroll
    for (int cpi = 0; cpi < 4; cpi++) {
        int chf = fch0 + 2 * cpi;
        int chc = 128 + chf;
        float s0 = 0.f, s1 = 0.f;
        if (act) {
            const uint2* rf0 = (const uint2*)(gt + (size_t)chf * NM + col0);
            const uint2* rf1 = (const uint2*)(gt + (size_t)(chf + 1) * NM + col0);
            const uint2* rc0 = (const uint2*)(gt + (size_t)chc * NM + col0);
            const uint2* rc1 = (const uint2*)(gt + (size_t)(chc + 1) * NM + col0);
            float aF0 = affA[w * 16 + 2 * cpi],     cF0 = affC[w * 16 + 2 * cpi];
            float aF1 = affA[w * 16 + 2 * cpi + 1], cF1 = affC[w * 16 + 2 * cpi + 1];
            float aC0 = affA[w * 16 + 8 + 2 * cpi],     cC0 = affC[w * 16 + 8 + 2 * cpi];
            float aC1 = affA[w * 16 + 8 + 2 * cpi + 1], cC1 = affC[w * 16 + 8 + 2 * cpi + 1];
            #pragma unroll
            for (int u = 0; u < 3; u++) {   // 3 x uint2 = 12 bonds
                uint2 f0 = rf0[u], f1 = rf1[u], k0 = rc0[u], k1 = rc1[u];
                #pragma unroll
                for (int h = 0; h < 4; h++) {
                    unsigned int fw0 = (h < 2) ? f0.x : f0.y;
                    unsigned int fw1 = (h < 2) ? f1.x : f1.y;
                    unsigned int kw0 = (h < 2) ? k0.x : k0.y;
                    unsigned int kw1 = (h < 2) ? k1.x : k1.y;
                    float gf0 = (h & 1) ? bhi(fw0) : blo(fw0);
                    float gf1 = (h & 1) ? bhi(fw1) : blo(fw1);
                    float gc0 = (h & 1) ? bhi(kw0) : blo(kw0);
                    float gc1 = (h & 1) ? bhi(kw1) : blo(kw1);
                    s0 += sigmoid_fast(fmaf(aF0, gf0, cF0)) * leakyf(fmaf(aC0, gc0, cC0));
                    s1 += sigmoid_fast(fmaf(aF1, gf1, cF1)) * leakyf(fmaf(aC1, gc1, cC1));
                }
            }
            *(float2*)(summed + (size_t)n * AFEA + chf) = make_float2(s0, s1);
        }
        float q0 = s0 * s0, q1 = s1 * s1;
        #pragma unroll
        for (int sft = 32; sft > 0; sft >>= 1) {
            s0 += __shfl_xor(s0, sft);
            s1 += __shfl_xor(s1, sft);
            q0 += __shfl_xor(q0, sft);
            q1 += __shfl_xor(q1, sft);
        }
        if (l == 0) {
            atomicAdd(&pp[chf], s0);
            atomicAdd(&pp[chf + 1], s1);
            atomicAdd(&pp[128 + chf], q0);
            atomicAdd(&pp[128 + chf + 1], q1);
        }
    }
}

// ---------------- residual update: fused bn2-finalize + af = leaky(af + bn2(summed)) ----------------
// block: 256 thr, 16 atoms (2048 elements).
__global__ __launch_bounds__(256) void afup_kernel(
    float* __restrict__ af, unsigned short* __restrict__ af16,
    const float* __restrict__ summed, const float* __restrict__ part2,
    const float* __restrict__ gamma2, const float* __restrict__ beta2,
    float cnt2, int total)
{
    __shared__ float a2s[128], c2s[128];
    int t = threadIdx.x;
    if (t < 128) {
        float s = 0.f, qq = 0.f;
        #pragma unroll
        for (int p = 0; p < P2; p++) {
            s += part2[(size_t)p * 256 + t];
            qq += part2[(size_t)p * 256 + 128 + t];
        }
        float mean = s / cnt2;
        float var = fmaxf(qq / cnt2 - mean * mean, 0.f);
        float a = gamma2[t] * rsqrtf(var + 1e-5f);
        a2s[t] = a;
        c2s[t] = beta2[t] - mean * a;
    }
    __syncthreads();
    int o = t & 127;
    float a2 = a2s[o], c2 = c2s[o];
    int base = blockIdx.x * 2048 + t;
    #pragma unroll
    for (int k = 0; k < 8; k++) {
        int i = base + k * 256;
        if (i < total) {
            float v = af[i] + a2 * summed[i] + c2;
            v = (v >= 0.f) ? v : 0.01f * v;
            af[i] = v;
            af16[i] = bfbits(v);
        }
    }
}

// ---------------- head: fused bn-finalize + both heads; thread owns 2 bonds ----------------
__global__ __launch_bounds__(256) void head_kernel(
    const unsigned short* __restrict__ gt, const float* __restrict__ part1,
    const float* __restrict__ dbg, const float* __restrict__ cbg,
    const float* __restrict__ dbb, const float* __restrict__ cbb,
    const float* __restrict__ w2d, const float* __restrict__ b2d,
    const float* __restrict__ w2c, const float* __restrict__ b2c,
    const float* __restrict__ pos, const float* __restrict__ off,
    const float* __restrict__ cells, const int* __restrict__ idx,
    float* __restrict__ out, float cnt1, int NM, int M)
{
    __shared__ float a_s[256], c_s[256], w_s[256];
    int t = threadIdx.x;
    {
        float s = 0.f, qq = 0.f;
        #pragma unroll 8
        for (int p = 0; p < P1; p++) {
            s += part1[(size_t)p * 512 + t];
            qq += part1[(size_t)p * 512 + 256 + t];
        }
        float mean = s / cnt1;
        float var = fmaxf(qq / cnt1 - mean * mean, 0.f);
        float g  = (t < 128) ? dbg[t] : cbg[t - 128];
        float be = (t < 128) ? dbb[t] : cbb[t - 128];
        float a = g * rsqrtf(var + 1e-5f);
        a_s[t] = a;
        c_s[t] = be - mean * a;
        w_s[t] = (t < 128) ? w2d[t] : w2c[t - 128];
    }
    __syncthreads();

    int e = blockIdx.x * 512 + t * 2;
    if (e >= NM) return;
    float sd0 = 0.f, sd1 = 0.f, sc0 = 0.f, sc1 = 0.f;
    #pragma unroll 4
    for (int ch = 0; ch < 128; ch++) {
        unsigned int u = *(const unsigned int*)(gt + (size_t)ch * NM + e);
        float a = a_s[ch], c = c_s[ch], wv = w_s[ch];
        sd0 += leakyf(fmaf(a, blo(u), c)) * wv;
        sd1 += leakyf(fmaf(a, bhi(u), c)) * wv;
    }
    #pragma unroll 4
    for (int ch = 128; ch < 256; ch++) {
        unsigned int u = *(const unsigned int*)(gt + (size_t)ch * NM + e);
        float a = a_s[ch], c = c_s[ch], wv = w_s[ch];
        sc0 += softplus_fast(fmaf(a, blo(u), c)) * wv;
        sc1 += softplus_fast(fmaf(a, bhi(u), c)) * wv;
    }
    float dist[2];
    #pragma unroll
    for (int h = 0; h < 2; h++) {
        int eb = e + h;
        int n = eb / M;
        int j = idx[eb];
        float o0 = off[(size_t)eb * 3 + 0];
        float o1 = off[(size_t)eb * 3 + 1];
        float o2 = off[(size_t)eb * 3 + 2];
        float d0 = o0 * cells[0] + o1 * cells[3] + o2 * cells[6] + pos[(size_t)j * 3 + 0] - pos[(size_t)n * 3 + 0];
        float d1 = o0 * cells[1] + o1 * cells[4] + o2 * cells[7] + pos[(size_t)j * 3 + 1] - pos[(size_t)n * 3 + 1];
        float d2 = o0 * cells[2] + o1 * cells[5] + o2 * cells[8] + pos[(size_t)j * 3 + 2] - pos[(size_t)n * 3 + 2];
        dist[h] = sqrtf(d0 * d0 + d1 * d1 + d2 * d2 + 1e-12f);
    }
    float bd = b2d[0], bc = b2c[0];
    float4 o4;
    o4.x = leakyf(sd0 + bd + dist[0]);
    o4.y = softplus_fast(sc0 + bc);
    o4.z = leakyf(sd1 + bd + dist[1]);
    o4.w = softplus_fast(sc1 + bc);
    *(float4*)(out + (size_t)e * 2) = o4;
}

extern "C" void kernel_launch(void* const* d_in, const int* in_sizes, int n_in,
                              void* d_out, int out_size, void* d_ws, size_t ws_size,
                              hipStream_t stream) {
    const float* atom_fea   = (const float*)d_in[0];
    const float* nbr_fea    = (const float*)d_in[1];
    const float* nbr_off    = (const float*)d_in[2];
    const float* atom_pos   = (const float*)d_in[3];
    const float* cells      = (const float*)d_in[4];
    const int*   idx        = (const int*)d_in[5];
    const float* emb_W      = (const float*)d_in[6];
    const float* emb_b      = (const float*)d_in[7];
    const float* convs_W    = (const float*)d_in[8];
    const float* convs_b    = (const float*)d_in[9];
    const float* bn1g       = (const float*)d_in[10];
    const float* bn1b       = (const float*)d_in[11];
    const float* bn2g       = (const float*)d_in[12];
    const float* bn2b       = (const float*)d_in[13];
    const float* dist_W     = (const float*)d_in[14];
    const float* dist_b     = (const float*)d_in[15];
    const float* dist_bn_g  = (const float*)d_in[16];
    const float* dist_bn_b  = (const float*)d_in[17];
    const float* dist2_W    = (const float*)d_in[18];
    const float* dist2_b    = (const float*)d_in[19];
    const float* const_W    = (const float*)d_in[20];
    const float* const_b    = (const float*)d_in[21];
    const float* const_bn_g = (const float*)d_in[22];
    const float* const_bn_b = (const float*)d_in[23];
    const float* const2_W   = (const float*)d_in[24];
    const float* const2_b   = (const float*)d_in[25];

    const int N  = in_sizes[0] / 92;
    const int M  = in_sizes[5] / N;
    const int NM = N * M;

    char* ws = (char*)d_ws;
    size_t off = 0;
    float* af             = (float*)(ws + off); off += (size_t)N * AFEA * 4;
    float* summed         = (float*)(ws + off); off += (size_t)N * AFEA * 4;
    unsigned short* af16  = (unsigned short*)(ws + off); off += (size_t)N * AFEA * 2;
    unsigned short* Wb    = (unsigned short*)(ws + off); off += (size_t)256 * KP * 2;
    float* part1          = (float*)(ws + off); off += (size_t)P1 * 512 * 4;
    float* part2          = (float*)(ws + off); off += (size_t)P2 * 256 * 4;
    unsigned short* g_t   = (unsigned short*)(ws + off); off += (size_t)NM * 256 * 2;
    unsigned short* nbr16 = (unsigned short*)(ws + off); off += (size_t)NM * 64 * 2;

    const int NPART = P1 * 512 + P2 * 256;   // part1+part2 contiguous

    nbr16_kernel<<<(NM * 64 + 255) / 256, 256, 0, stream>>>(nbr_fea, nbr16, NM);
    embed_kernel<<<(N + 15) / 16, 256, 0, stream>>>(atom_fea, emb_W, emb_b, af, af16, N);

    const int gblocks = NM / ROWS;
    const int gateblocks = ((N + 63) / 64) * 4;
    const int prepblocks = (256 * KP + 255) / 256;

    for (int i = 0; i < 3; i++) {
        size_t wo  = (size_t)i * 256 * IN2;
        size_t bo  = (size_t)i * 256;
        size_t b2o = (size_t)i * 128;

        prep_kernel<<<prepblocks, 256, 0, stream>>>(
            convs_W, wo, convs_W, wo + (size_t)128 * IN2, Wb, part1, NPART);
        gemm_mfma_kernel<<<gblocks, 256, 0, stream>>>(
            af16, nbr16, idx, Wb, convs_b, bo, convs_b, bo + 128,
            g_t, part1, NM, M);
        gate_kernel<<<gateblocks, 256, 0, stream>>>(
            g_t, part1, bn1g + bo, bn1b + bo, summed, part2, (float)NM, N, M, NM);
        afup_kernel<<<(N * AFEA + 2047) / 2048, 256, 0, stream>>>(
            af, af16, summed, part2, bn2g + b2o, bn2b + b2o, (float)N, N * AFEA);
    }

    // heads: fused 297->256 GEMM (cols 0..127 dist, 128..255 const)
    {
        prep_kernel<<<prepblocks, 256, 0, stream>>>(
            dist_W, 0, const_W, 0, Wb, part1, P1 * 512);
        gemm_mfma_kernel<<<gblocks, 256, 0, stream>>>(
            af16, nbr16, idx, Wb, dist_b, 0, const_b, 0,
            g_t, part1, NM, M);
        head_kernel<<<(NM + 511) / 512, 256, 0, stream>>>(
            g_t, part1, dist_bn_g, const_bn_g, dist_bn_b, const_bn_b,
            dist2_W, dist2_b, const2_W, const2_b,
            atom_pos, nbr_off, cells, idx, (float*)d_out, (float)NM, NM, M);
    }
}